// Round 13
// baseline (51.010 us; speedup 1.0000x reference)
//
#include <hip/hip_runtime.h>
#include <stdint.h>

// Reference: pos += fl32(vel*dt); vel += fl32(fl32(-9.81)*fl32(0.01)); record pos.
// Exact emulation of the f32 scan via piecewise-constant-increment runs.
// r13 = r12 fused kernel with occupancy-exact launch: grid 1024 +
// __launch_bounds__(256,4) -> exactly one resident round (r12's 48.8us was two
// sequential rounds of blocks, each re-paying the redundant per-block prep).
// Staircase now early-exits at each block's own row_end (early blocks build ~5
// links, not ~35); phase-2 run lengths clamped to the built prefix (soundness).
// Numeric bodies otherwise r12-verbatim (absmax invariant 2^28).

static constexpr long long NSTEPS = 10000000LL;  // output rows
static constexpr long long NS     = 4000000LL;   // model/event cutover (even)
static constexpr int SEGCAP = 384;               // vel segments (~70 real)
static constexpr int RUNCAP = 160;               // per-block pos runs (~25 real max)

__device__ __forceinline__ bool same_binade_f32(float a, float b) {
    return (((__float_as_uint(a) ^ __float_as_uint(b)) & 0xFF800000u) == 0u);
}
__device__ __forceinline__ unsigned expfield(float v) {
    return (__float_as_uint(v) >> 23) & 0xFFu;
}
__device__ __forceinline__ float pow2f(int e) {   // e in (-127, 128)
    return __uint_as_float((unsigned)(e + 127) << 23);
}
__device__ __forceinline__ double pow2d(int e) {  // e in (-1023, 1024)
    return __longlong_as_double(((long long)(e + 1023)) << 52);
}
__device__ __forceinline__ int bin_k_d(double v) {
    return (int)((__double_as_longlong(v) >> 52) & 0x7FFll) - 1022;
}

__global__ __launch_bounds__(256, 4) void fused(
        const float* __restrict__ pos0, const float* __restrict__ vel0,
        float4* __restrict__ out, long long npairs)
{
    __shared__ int    s_m[SEGCAP + 1];
    __shared__ double s_c[SEGCAP], s_V[SEGCAP], s_P[SEGCAP];
    __shared__ int    s_nseg, s_bad, s_nrun;
    __shared__ long long s_mstop;                    // steps actually built
    __shared__ int    r_n[RUNCAP];
    __shared__ double r_p[RUNCAP], r_i[RUNCAP];

    const int tid  = threadIdx.x;
    const int lane = tid & 63;
    const int wv   = tid >> 6;

    // Block-contiguous range of float4s (whole pairs; NS even => no straddle).
    const long long per = (npairs + (long long)gridDim.x - 1) / (long long)gridDim.x;
    const long long i0 = (long long)blockIdx.x * per;
    long long i1 = i0 + per; if (i1 > npairs) i1 = npairs;
    if (i0 >= npairs) return;                        // block-uniform exit
    const long long row_end = 2 * i1;                // exclusive last row + 1
    const long long mstop = row_end;                 // staircase needed to here

    const float dtf  = 0.01f;
    const float gdtf = __fmul_rn(-9.81f, dtf);
    const double dtd = (double)dtf, gcd = (double)gdtf;

    // Unique tie binade: gc = -M*2^E (M odd); tie iff k = E+25.
    int k_tie;
    {
        unsigned g = __float_as_uint(gdtf);
        unsigned mant = (g & 0x7FFFFFu) | 0x800000u;
        int tz = __ffs((int)mant) - 1;
        int E = (int)((g >> 23) & 0xFFu) - 127 - 23 + tz;
        k_tie = E + 25;
    }

    // ===== Phase 1a (tid 0): ANALYTIC vel staircase to mstop ================
    if (tid == 0) {
        s_nrun = 0;
        bool bad = false;
        double V = (double)vel0[1];
        double P = (double)pos0[1];   // model pos prefix: p0 + dt*sum(vel_k)
        long long m = 0;
        int nseg = 0;
        while (m < mstop) {
            if (nseg >= SEGCAP - 2) { bad = true; break; }
            const float vf = (float)V;
            const float vn1 = __fadd_rn(vf, gdtf);
            const double c = (double)vn1 - V;
            bad = bad | ((double)vf != V) | !(c < 0.0);
            if (bad) break;
            const long long rem = mstop - m;

            long long T = 0;
            const unsigned ef = expfield(vf);
            if (ef != 0u && ef != 0xFFu) {
                const int k = (int)ef - 126;            // |vf| in [2^(k-1),2^k)
                if (k != k_tie) {
                    const double B = (V > 0.0) ? pow2d(k - 1) : -pow2d(k);
                    float tt = __fdividef((float)(V + gcd - B), (float)(-c)) + 1.0f;
                    T = (tt > 0.0f) ? (long long)tt : 0;
                    if (T > rem + 4) T = rem + 4;
                    if (V > 0.0) {                      // stay iff V+(t-1)c+gc >= B
                        T -= (long long)((T > 0) && (V + (double)(T - 1) * c + gcd <  B));
                        T -= (long long)((T > 0) && (V + (double)(T - 1) * c + gcd <  B));
                        T -= (long long)((T > 0) && (V + (double)(T - 1) * c + gcd <  B));
                        T += (long long)(V + (double)T * c + gcd >= B);
                        T += (long long)(V + (double)T * c + gcd >= B);
                        T += (long long)(V + (double)T * c + gcd >= B);
                    } else {                            // stay iff V+(t-1)c+gc > B
                        T -= (long long)((T > 0) && (V + (double)(T - 1) * c + gcd <= B));
                        T -= (long long)((T > 0) && (V + (double)(T - 1) * c + gcd <= B));
                        T -= (long long)((T > 0) && (V + (double)(T - 1) * c + gcd <= B));
                        T += (long long)(V + (double)T * c + gcd >  B);
                        T += (long long)(V + (double)T * c + gcd >  B);
                        T += (long long)(V + (double)T * c + gcd >  B);
                    }
                    if (T < 0) T = 0;
                }
            }
            if (T > rem) T = rem;
            if (T > 0) {                                // main segment
                s_m[nseg] = (int)m; s_V[nseg] = V; s_c[nseg] = c; s_P[nseg] = P; ++nseg;
                P += dtd * ((double)T * V + c * ((double)T * (double)(T - 1) * 0.5));
                V += (double)T * c;                     // exact dyadics
                m += T;
                if (m >= mstop) break;
            }
            // fused boundary 1-step link
            const float vf2 = (float)V;
            bad = bad | ((double)vf2 != V);
            if (bad) break;
            const float vb = __fadd_rn(vf2, gdtf);
            const double cb = (double)vb - V;
            s_m[nseg] = (int)m; s_V[nseg] = V; s_c[nseg] = cb; s_P[nseg] = P; ++nseg;
            P += dtd * V;
            V += cb;
            m += 1;
        }
        bad = bad | (m < mstop);
        s_bad = bad ? 1 : 0;
        s_nseg = nseg;
        s_mstop = m;                                    // actual built prefix
        s_m[nseg] = 0x7fffffff;                         // sentinel
    }
    __syncthreads();

    // ===== Phase 1b (wave 0): wave-parallel verification ====================
    if (wv == 0 && !s_bad) {
        const int nseg = s_nseg;
        const long long mbuilt = s_mstop;
        bool ok = (nseg > 0);
        for (int i = lane; i < nseg; i += 64) {
            const double Vi = s_V[i], ci = s_c[i];
            const long long mi = s_m[i];
            const long long me = (i + 1 < nseg) ? (long long)s_m[i + 1] : mbuilt;
            const long long len = me - mi;
            ok = ok && (len >= 1);
            const float vfi = (float)Vi;
            ok = ok && ((double)vfi == Vi);
            const float vn = __fadd_rn(vfi, gdtf);
            ok = ok && ((double)vn - Vi == ci);         // start increment
            const double Ve = Vi + (double)(len - 1) * ci;
            const float vfe = (float)Ve;
            ok = ok && ((double)vfe == Ve);             // end representable
            const float vne = __fadd_rn(vfe, gdtf);
            ok = ok && ((double)vne - Ve == ci);        // end increment
            if (len > 1) {
                const unsigned efi = expfield(vfi);
                ok = ok && (efi != 0u) && (efi != 0xFFu);
                const int kk = (int)efi - 126;
                ok = ok && same_binade_f32(vfe, vfi);   // v stays in binade
                ok = ok && (bin_k_d(Vi + gcd) == kk);   // pre-rounds stay too
                ok = ok && (bin_k_d(Ve + gcd) == kk);
                ok = ok && (kk != k_tie);               // non-tie binade
            }
            if (i + 1 < nseg)
                ok = ok && (s_V[i + 1] == Vi + (double)len * ci);  // chain
        }
        const unsigned long long good = __ballot(ok);
        if (lane == 0 && good != ~0ULL) s_bad = 1;
    }
    __syncthreads();

    // ===== Phase 1c (wave 0): fallback — serial ballot staircase ============
    if (wv == 0 && s_bad) {
        double V = (double)vel0[1];
        double P = (double)pos0[1];
        long long m = 0;
        int nseg = 0;
        while (m < mstop && nseg < SEGCAP) {
            const float vf  = (float)V;
            const float vn1 = __fadd_rn(vf, gdtf);
            const double c  = (double)vn1 - V;
            const long long rem = mstop - m;
            long long Lb = rem;
            const float cf = (float)c;
            const unsigned ef = expfield(vf);
            if (vf == 0.0f || ef == 0u) {
                Lb = 64;
            } else if (cf != 0.0f) {
                const int k = (int)ef - 126;
                float s = vf < 0.0f ? -1.0f : 1.0f;
                float B = ((vf < 0.0f) == (cf < 0.0f)) ? s * pow2f(k) : s * pow2f(k - 1);
                float r = __fdividef(B - vf, cf);
                if (r >= 0.0f && r < 4.0e9f) Lb = (long long)r + 1;
            }
            long long Lhi = Lb + 2;
            if (Lhi > rem) Lhi = rem;
            if (Lhi < 1) Lhi = 1;

            long long L = 1, base = Lhi;
            for (int round = 0; round < 32; ++round) {
                const long long candL = base - 63 + (long long)lane;
                bool valid = false;
                if (candL >= 1) {
                    const double ve = V + (double)(candL - 1) * c;
                    const float vef = (float)ve;
                    const float vn2 = __fadd_rn(vef, gdtf);
                    valid = ((double)vef == ve)
                         && same_binade_f32(vef, vf)
                         && ((double)vn2 - ve == c);
                }
                unsigned long long msk = __ballot(valid);
                if (msk) { L = base - 63 + (long long)(63 - __clzll(msk)); break; }
                base -= 64;
                if (base < 1) break;
            }
            if (L < 1) L = 1;
            if (L > rem) L = rem;

            if (lane == 0) { s_m[nseg] = (int)m; s_V[nseg] = V; s_c[nseg] = c; s_P[nseg] = P; }
            ++nseg;
            P += dtd * ((double)L * V + c * ((double)L * (double)(L - 1) * 0.5));
            V += (double)L * c;
            m += L;
        }
        if (lane == 0) { s_nseg = nseg; s_mstop = m; s_m[nseg] = 0x7fffffff; }
    }
    __syncthreads();

    // ===== Phase 2 (wave 0): pos run-chain from NS to THIS block's end ======
    if (wv == 0 && row_end > NS) {
        const int nseg = s_nseg;
        const long long mbuilt = s_mstop;
        int lo = 0, hi = nseg - 1;
        while (lo < hi) { int mid = (lo + hi + 1) >> 1;
                          if ((long long)s_m[mid] <= NS) lo = mid; else hi = mid - 1; }
        int jj = lo;
        const double t0 = (double)(NS - s_m[jj]);
        double vel = s_V[jj] + t0 * s_c[jj];            // exact scan vel at NS
        double P2  = s_P[jj] + dtd * (t0 * s_V[jj] + s_c[jj] * (t0 * (t0 - 1.0) * 0.5));
        double pos = (double)(float)P2;                 // snap model pos to grid
        long long n = NS;
        int nrun = 0;
        long long nend = (row_end < NSTEPS - 1) ? row_end : (NSTEPS - 1);
        if (nend > mbuilt) nend = mbuilt;
        while (n < nend && nrun < RUNCAP) {
            while (s_m[jj + 1] <= (int)n) ++jj;         // sentinel stops
            const double cv = s_c[jj];
            long long Lcap = (long long)s_m[jj + 1] - n;
            if (Lcap > mbuilt - n) Lcap = mbuilt - n;   // never extrapolate cv
            const long long rem = (NSTEPS - 1) - n;
            if (Lcap > rem) Lcap = rem;

            const float pf = (float)pos;
            const float vf2 = (float)vel;
            const float dstep = __fmul_rn(vf2, dtf);
            const float pn1 = __fadd_rn(pf, dstep);
            const double inc = (double)pn1 - pos;       // exact f32 pos increment

            long long La = Lcap, Lc = Lcap;
            const float incf = (float)inc;
            const unsigned efp = expfield(pf);
            if (pf == 0.0f || efp == 0u) {
                La = 64;
            } else if (incf != 0.0f) {                  // pos binade exit
                const int k = (int)efp - 126;
                float s = pf < 0.0f ? -1.0f : 1.0f;
                float B = ((pf < 0.0f) == (incf < 0.0f)) ? s * pow2f(k) : s * pow2f(k - 1);
                float r = __fdividef(B - pf, incf);
                if (r >= 0.0f && r < 4.0e9f) { La = (long long)r - 1; if (La < 0) La = 0; }
            }
            const double dd = cv * dtd;
            if (dd != 0.0 && pf != 0.0f && efp != 0u) { // increment cell crossing
                const int k = (int)efp - 126;
                if (k - 24 > -126) {
                    const float ulpf = pow2f(k - 24);
                    const double d0 = (double)dstep;
                    const double T = inc + (dd < 0.0 ? -0.5 : 0.5) * (double)ulpf;
                    float r = __fdividef((float)(T - d0), (float)dd);
                    if (r >= 0.0f && r < 4.0e9f) { Lc = (long long)r + 2; if (Lc < 1) Lc = 1; }
                }
            }
            long long Lhi = La < Lc ? La : Lc;
            Lhi += 3;
            if (Lhi > Lcap) Lhi = Lcap;
            if (Lhi < 1) Lhi = 1;

            long long L = 1, base = Lhi;
            for (int round = 0; round < 32; ++round) {
                const long long candL = base - 63 + (long long)lane;
                bool valid = false;
                if (candL >= 1) {
                    const double pe = pos + (double)(candL - 1) * inc;  // exact dyadics
                    const double ve = vel + (double)(candL - 1) * cv;
                    const float pef = (float)pe;
                    const float vef = (float)ve;
                    const float d2  = __fmul_rn(vef, dtf);
                    const float pn2 = __fadd_rn(pef, d2);
                    valid = ((double)pef == pe)
                         && same_binade_f32(pef, pf)
                         && ((double)vef == ve)
                         && ((double)pn2 - pe == inc);
                }
                unsigned long long msk = __ballot(valid);
                if (msk) { L = base - 63 + (long long)(63 - __clzll(msk)); break; }
                base -= 64;
                if (base < 1) break;
            }
            if (L < 1) L = 1;
            if (L > Lcap) L = Lcap;
            if (L < 1) L = 1;

            if (lane == 0) { r_n[nrun] = (int)n; r_p[nrun] = pos; r_i[nrun] = inc; }
            ++nrun;
            pos += (double)L * inc;                     // exact dyadics
            vel += (double)L * cv;
            n += L;
        }
        if (lane == 0) s_nrun = nrun;
    }
    __syncthreads();

    // ===== Fill: this block's contiguous range ==============================
    const int nseg = s_nseg;
    const int nrun = s_nrun;
    const double p0x = (double)pos0[0];
    const double cx  = (double)__fmul_rn(vel0[0], dtf);  // constant f32 x-increment

    const long long ii = i0 + tid;
    if (ii >= i1) return;

    int j, r = 0;
    {   // one locate per thread, then monotone walk
        const int t0 = (int)(2 * ii);
        int lo = 0, hi = nseg - 1;
        while (lo < hi) { int mid = (lo + hi + 1) >> 1; if (s_m[mid] <= t0) lo = mid; else hi = mid - 1; }
        j = lo;
        if (nrun > 0) {
            int rlo = 0, rhi = nrun - 1;
            while (rlo < rhi) { int mid = (rlo + rhi + 1) >> 1; if (r_n[mid] <= t0) rlo = mid; else rhi = mid - 1; }
            r = rlo;
        }
    }
    for (long long i = ii; i < i1; i += blockDim.x) {
        const long long m0 = 2 * i, m1 = m0 + 1;
        float4 o;
        o.x = (float)(p0x + (double)m0 * cx);
        o.z = (float)(p0x + (double)m1 * cx);
        const int t0 = (int)m0;

        if (m1 < NS || nrun <= 0) {  // exact-vel integral model (NS even)
            while (s_m[j + 1] <= t0) ++j;                // monotone walk
            double t = (double)(m0 - s_m[j]);
            o.y = (float)(s_P[j] + dtd * (t * s_V[j] + s_c[j] * (t * (t - 1.0) * 0.5)));
            const int j1 = (s_m[j + 1] <= (int)m1) ? j + 1 : j;
            t = (double)(m1 - s_m[j1]);
            o.w = (float)(s_P[j1] + dtd * (t * s_V[j1] + s_c[j1] * (t * (t - 1.0) * 0.5)));
        } else {                     // run-event region
            while (r + 1 < nrun && r_n[r + 1] <= t0) ++r;
            o.y = (float)(r_p[r] + (double)(m0 - r_n[r]) * r_i[r]);
            const int r1 = (r + 1 < nrun && r_n[r + 1] <= (int)m1) ? r + 1 : r;
            o.w = (float)(r_p[r1] + (double)(m1 - r_n[r1]) * r_i[r1]);
        }
        out[i] = o;
    }
}

extern "C" void kernel_launch(void* const* d_in, const int* in_sizes, int n_in,
                              void* d_out, int out_size, void* d_ws, size_t ws_size,
                              hipStream_t stream) {
    // Inputs: [0] ball_mass (unused), [1] initial_position[2], [2] initial_velocity[2].
    const float* pos0 = (const float*)d_in[1];
    const float* vel0 = (const float*)d_in[2];

    const long long npairs = (long long)out_size / 4;  // 5,000,000 float4s
    // grid 1024 = 256 CU x 4 blocks/CU (launch_bounds caps VGPR so 4 fit):
    // exactly ONE resident round -> redundant per-block prep paid once.
    fused<<<1024, 256, 0, stream>>>(pos0, vel0, (float4*)d_out, npairs);
}

// Round 14
// 42.959 us; speedup vs baseline: 1.1874x; 1.1874x over previous
//
#include <hip/hip_runtime.h>
#include <stdint.h>

// Reference: pos += fl32(vel*dt); vel += fl32(fl32(-9.81)*fl32(0.01)); record pos.
// Exact emulation of the f32 scan via piecewise-constant-increment runs.
// r14: single fused kernel, ONE staircase path (ballot, r6-proven; analytic+
// verifier+fallback trio deleted — r8-r11 showed no benefit). Three regions:
//   [0, NPOLY=1e6):  pure f64 polynomial (r5-proven) — zero prep.
//   [NPOLY, NS):     vel-staircase segment quadratics (ballot-built to row_end).
//   [NS=5.5e6, 1e7): pos run-events (ballot; ~9 events; anchor sawtooth at
//                    5.5e6 = 1024^2/(8*0.00125) ~ 1.05e8, calibrated vs r7's
//                    measured 1.88e9 @ ulp 4096 — within budget).
// Grid 1024 + launch_bounds(256,4): one resident round. Worst-block chain ~
// 30 links + 9 events.

static constexpr long long NSTEPS = 10000000LL;  // output rows
static constexpr long long NPOLY  = 1000000LL;   // polynomial cutover (even)
static constexpr long long NS     = 5500000LL;   // model/run cutover (even)
static constexpr int SEGCAP = 384;               // vel segments (~70 real)
static constexpr int RUNCAP = 96;                // per-block pos runs (~12 real)

__device__ __forceinline__ bool same_binade_f32(float a, float b) {
    return (((__float_as_uint(a) ^ __float_as_uint(b)) & 0xFF800000u) == 0u);
}
__device__ __forceinline__ unsigned expfield(float v) {
    return (__float_as_uint(v) >> 23) & 0xFFu;
}
__device__ __forceinline__ float pow2f(int e) {   // e in (-127, 128)
    return __uint_as_float((unsigned)(e + 127) << 23);
}

__global__ __launch_bounds__(256, 4) void fused(
        const float* __restrict__ pos0, const float* __restrict__ vel0,
        float4* __restrict__ out, long long npairs)
{
    __shared__ int    s_m[SEGCAP + 1];
    __shared__ double s_c[SEGCAP], s_V[SEGCAP], s_P[SEGCAP];
    __shared__ int    s_nseg, s_nrun;
    __shared__ long long s_mstop;
    __shared__ int    r_n[RUNCAP];
    __shared__ double r_p[RUNCAP], r_i[RUNCAP];

    const int tid  = threadIdx.x;
    const int lane = tid & 63;
    const int wv   = tid >> 6;

    // Block-contiguous range of float4s (NPOLY/NS even => pairs never straddle).
    const long long per = (npairs + (long long)gridDim.x - 1) / (long long)gridDim.x;
    const long long i0 = (long long)blockIdx.x * per;
    long long i1 = i0 + per; if (i1 > npairs) i1 = npairs;
    if (i0 >= npairs) return;                        // block-uniform exit
    const long long row_end = 2 * i1;
    const long long mstop = row_end < NSTEPS ? row_end : NSTEPS;

    const float dtf  = 0.01f;
    const float gdtf = __fmul_rn(-9.81f, dtf);
    const double dtd = (double)dtf, gdtd = (double)gdtf;
    const double p0y = (double)pos0[1], v0y = (double)vel0[1];

    if (tid == 0) { s_nseg = 0; s_nrun = 0; s_mstop = 0; }
    __syncthreads();

    // ===== Staircase (wave 0): ballot-verified vel runs from 0 to mstop =====
    if (wv == 0 && row_end > NPOLY) {
        double V = v0y, P = p0y;
        long long m = 0;
        int nseg = 0;
        while (m < mstop && nseg < SEGCAP) {
            const float vf  = (float)V;
            const float vn1 = __fadd_rn(vf, gdtf);
            const double c  = (double)vn1 - V;           // exact f32 increment
            const long long rem = mstop - m;
            long long Lb = rem;
            const float cf = (float)c;
            const unsigned ef = expfield(vf);
            if (vf == 0.0f || ef == 0u) {
                Lb = 64;
            } else if (cf != 0.0f) {                     // binade-exit bound
                const int k = (int)ef - 126;
                float s = vf < 0.0f ? -1.0f : 1.0f;
                float B = ((vf < 0.0f) == (cf < 0.0f)) ? s * pow2f(k) : s * pow2f(k - 1);
                float r = __fdividef(B - vf, cf);
                if (r >= 0.0f && r < 4.0e9f) Lb = (long long)r + 1;
            }
            long long Lhi = Lb + 2;
            if (Lhi > rem) Lhi = rem;
            if (Lhi < 1) Lhi = 1;

            long long L = 1, base = Lhi;                 // highest-valid ballot
            for (int round = 0; round < 32; ++round) {
                const long long candL = base - 63 + (long long)lane;
                bool valid = false;
                if (candL >= 1) {
                    const double ve = V + (double)(candL - 1) * c;  // exact dyadics
                    const float vef = (float)ve;
                    const float vn2 = __fadd_rn(vef, gdtf);
                    valid = ((double)vef == ve)
                         && same_binade_f32(vef, vf)
                         && ((double)vn2 - ve == c);
                }
                unsigned long long msk = __ballot(valid);
                if (msk) { L = base - 63 + (long long)(63 - __clzll(msk)); break; }
                base -= 64;
                if (base < 1) break;                     // L=1 always valid
            }
            if (L < 1) L = 1;
            if (L > rem) L = rem;

            if (lane == 0) { s_m[nseg] = (int)m; s_V[nseg] = V; s_c[nseg] = c; s_P[nseg] = P; }
            ++nseg;
            P += dtd * ((double)L * V + c * ((double)L * (double)(L - 1) * 0.5));
            V += (double)L * c;                          // exact dyadics
            m += L;
        }
        if (lane == 0) { s_nseg = nseg; s_mstop = m; s_m[nseg] = 0x7fffffff; }
    }
    __syncthreads();

    // ===== Phase 2 (wave 0): pos run-chain from NS to this block's end ======
    if (wv == 0 && row_end > NS && s_mstop >= NS) {
        const int nseg = s_nseg;
        const long long mbuilt = s_mstop;
        int lo = 0, hi = nseg - 1;
        while (lo < hi) { int mid = (lo + hi + 1) >> 1;
                          if ((long long)s_m[mid] <= NS) lo = mid; else hi = mid - 1; }
        int jj = lo;
        const double t0 = (double)(NS - s_m[jj]);
        double vel = s_V[jj] + t0 * s_c[jj];             // exact scan vel at NS
        double P2  = s_P[jj] + dtd * (t0 * s_V[jj] + s_c[jj] * (t0 * (t0 - 1.0) * 0.5));
        double pos = (double)(float)P2;                  // snap model pos to grid
        long long n = NS;
        int nrun = 0;
        long long nend = (row_end < NSTEPS - 1) ? row_end : (NSTEPS - 1);
        if (nend > mbuilt) nend = mbuilt;
        while (n < nend && nrun < RUNCAP) {
            while (s_m[jj + 1] <= (int)n) ++jj;          // sentinel stops
            const double cv = s_c[jj];
            long long Lcap = (long long)s_m[jj + 1] - n;
            if (Lcap > mbuilt - n) Lcap = mbuilt - n;    // never extrapolate cv
            const long long rem = (NSTEPS - 1) - n;
            if (Lcap > rem) Lcap = rem;

            const float pf = (float)pos;
            const float vf2 = (float)vel;
            const float dstep = __fmul_rn(vf2, dtf);
            const float pn1 = __fadd_rn(pf, dstep);
            const double inc = (double)pn1 - pos;        // exact f32 pos increment

            long long La = Lcap, Lc = Lcap;
            const float incf = (float)inc;
            const unsigned efp = expfield(pf);
            if (pf == 0.0f || efp == 0u) {
                La = 64;
            } else if (incf != 0.0f) {                   // pos binade exit
                const int k = (int)efp - 126;
                float s = pf < 0.0f ? -1.0f : 1.0f;
                float B = ((pf < 0.0f) == (incf < 0.0f)) ? s * pow2f(k) : s * pow2f(k - 1);
                float r = __fdividef(B - pf, incf);
                if (r >= 0.0f && r < 4.0e9f) { La = (long long)r - 1; if (La < 0) La = 0; }
            }
            const double dd = cv * dtd;
            if (dd != 0.0 && pf != 0.0f && efp != 0u) {  // increment cell crossing
                const int k = (int)efp - 126;
                if (k - 24 > -126) {
                    const float ulpf = pow2f(k - 24);
                    const double d0 = (double)dstep;
                    const double T = inc + (dd < 0.0 ? -0.5 : 0.5) * (double)ulpf;
                    float r = __fdividef((float)(T - d0), (float)dd);
                    if (r >= 0.0f && r < 4.0e9f) { Lc = (long long)r + 2; if (Lc < 1) Lc = 1; }
                }
            }
            long long Lhi = La < Lc ? La : Lc;
            Lhi += 3;
            if (Lhi > Lcap) Lhi = Lcap;
            if (Lhi < 1) Lhi = 1;

            long long L = 1, base = Lhi;
            for (int round = 0; round < 32; ++round) {
                const long long candL = base - 63 + (long long)lane;
                bool valid = false;
                if (candL >= 1) {
                    const double pe = pos + (double)(candL - 1) * inc;  // exact dyadics
                    const double ve = vel + (double)(candL - 1) * cv;
                    const float pef = (float)pe;
                    const float vef = (float)ve;
                    const float d2  = __fmul_rn(vef, dtf);
                    const float pn2 = __fadd_rn(pef, d2);
                    valid = ((double)pef == pe)
                         && same_binade_f32(pef, pf)
                         && ((double)vef == ve)
                         && ((double)pn2 - pe == inc);
                }
                unsigned long long msk = __ballot(valid);
                if (msk) { L = base - 63 + (long long)(63 - __clzll(msk)); break; }
                base -= 64;
                if (base < 1) break;
            }
            if (L < 1) L = 1;
            if (L > Lcap) L = Lcap;
            if (L < 1) L = 1;

            if (lane == 0) { r_n[nrun] = (int)n; r_p[nrun] = pos; r_i[nrun] = inc; }
            ++nrun;
            pos += (double)L * inc;                      // exact dyadics
            vel += (double)L * cv;
            n += L;
        }
        if (lane == 0) s_nrun = nrun;
    }
    __syncthreads();

    // ===== Fill: this block's contiguous range ==============================
    const int nseg = s_nseg;
    const int nrun = s_nrun;
    const double p0x = (double)pos0[0];
    const double cx  = (double)__fmul_rn(vel0[0], dtf);  // constant f32 x-increment

    const long long ii = i0 + tid;
    if (ii >= i1) return;

    int j = 0, r = 0;
    if (nseg > 0) {   // one locate per thread, then monotone walk
        const int t0 = (int)(2 * ii);
        int lo = 0, hi = nseg - 1;
        while (lo < hi) { int mid = (lo + hi + 1) >> 1; if (s_m[mid] <= t0) lo = mid; else hi = mid - 1; }
        j = lo;
        if (nrun > 0) {
            int rlo = 0, rhi = nrun - 1;
            while (rlo < rhi) { int mid = (rlo + rhi + 1) >> 1; if (r_n[mid] <= t0) rlo = mid; else rhi = mid - 1; }
            r = rlo;
        }
    }
    for (long long i = ii; i < i1; i += blockDim.x) {
        const long long m0 = 2 * i, m1 = m0 + 1;
        float4 o;
        o.x = (float)(p0x + (double)m0 * cx);
        o.z = (float)(p0x + (double)m1 * cx);
        const int t0 = (int)m0;

        if (m1 < NPOLY) {            // polynomial region (no tables)
            double md = (double)m0;
            o.y = (float)(p0y + dtd * (md * v0y) + (dtd * gdtd) * (md * (md - 1.0) * 0.5));
            md = (double)m1;
            o.w = (float)(p0y + dtd * (md * v0y) + (dtd * gdtd) * (md * (md - 1.0) * 0.5));
        } else if (m1 < NS || nrun <= 0) {  // staircase segment quadratics
            while (s_m[j + 1] <= t0) ++j;                // monotone walk
            double t = (double)(m0 - s_m[j]);
            o.y = (float)(s_P[j] + dtd * (t * s_V[j] + s_c[j] * (t * (t - 1.0) * 0.5)));
            const int j1 = (s_m[j + 1] <= (int)m1) ? j + 1 : j;
            t = (double)(m1 - s_m[j1]);
            o.w = (float)(s_P[j1] + dtd * (t * s_V[j1] + s_c[j1] * (t * (t - 1.0) * 0.5)));
        } else {                     // run-event region
            while (r + 1 < nrun && r_n[r + 1] <= t0) ++r;
            o.y = (float)(r_p[r] + (double)(m0 - r_n[r]) * r_i[r]);
            const int r1 = (r + 1 < nrun && r_n[r + 1] <= (int)m1) ? r + 1 : r;
            o.w = (float)(r_p[r1] + (double)(m1 - r_n[r1]) * r_i[r1]);
        }
        out[i] = o;
    }
}

extern "C" void kernel_launch(void* const* d_in, const int* in_sizes, int n_in,
                              void* d_out, int out_size, void* d_ws, size_t ws_size,
                              hipStream_t stream) {
    // Inputs: [0] ball_mass (unused), [1] initial_position[2], [2] initial_velocity[2].
    const float* pos0 = (const float*)d_in[1];
    const float* vel0 = (const float*)d_in[2];

    const long long npairs = (long long)out_size / 4;  // 5,000,000 float4s
    // grid 1024 = 256 CU x 4 blocks/CU: one resident round.
    fused<<<1024, 256, 0, stream>>>(pos0, vel0, (float4*)d_out, npairs);
}